// Round 3
// baseline (381.332 us; speedup 1.0000x reference)
//
#include <hip/hip_runtime.h>
#include <hip/hip_bf16.h>

#define NB   8
#define NPTS 16384
#define NS1  512
#define NS2  128
#define KNN  32
#define FINF 3.402823466e+38f

// float -> order-preserving unsigned (handles tiny negative d2 from cancellation)
__device__ __forceinline__ unsigned sortkey(float f) {
  unsigned u = __float_as_uint(f);
  unsigned m = (u & 0x80000000u) ? 0xFFFFFFFFu : 0x80000000u;
  return u ^ m;
}

// Distributed exact running top-32 (by u64 key) across lanes 0..31 of a wave.
// (per-insert tau update variant — used by knn2)
__device__ __forceinline__ void topk32_round(unsigned long long key, int lane,
                                             unsigned long long& lkey,
                                             unsigned long long& tau) {
  unsigned long long mask = __ballot(key < tau);
  while (mask) {
    int src = __ffsll(mask) - 1;
    mask &= mask - 1;
    unsigned long long cand = __shfl(key, src);
    if (cand < tau) {               // re-check: tau may have shrunk
      unsigned long long up = __shfl_up(lkey, 1);
      if (lane == 0) up = 0ull;
      unsigned long long nk = (lkey < cand) ? lkey : (up < cand ? cand : up);
      if (lane < 32) lkey = nk;
      tau = __shfl(lkey, 31);
    }
  }
}

// stale-tau variant: insert all ballot hits, tau refreshed by caller per tile.
// Exact: keys unique; skipped key >= tau(then) >= final tau => not in top-32.
__device__ __forceinline__ void topk32_tile(unsigned long long key, int lane,
                                            unsigned long long& lkey,
                                            unsigned long long& tau) {
  unsigned long long mask = __ballot(key < tau);
  while (mask) {
    int src = __ffsll(mask) - 1;
    mask &= mask - 1;
    unsigned long long cand = __shfl(key, src);
    unsigned long long up = __shfl_up(lkey, 1);
    if (lane == 0) up = 0ull;
    unsigned long long nk = (lkey < cand) ? lkey : (up < cand ? cand : up);
    if (lane < 32) lkey = nk;
  }
  tau = __shfl(lkey, 31);
}

// Merge this lane's sorted top-3 (d,j) with xor-partner's, lexicographic (d, j).
__device__ __forceinline__ void merge3(float& d0, int& j0, float& d1, int& j1,
                                       float& d2, int& j2, int xm) {
  float e0 = __shfl_xor(d0, xm), e1 = __shfl_xor(d1, xm), e2 = __shfl_xor(d2, xm);
  int   f0 = __shfl_xor(j0, xm), f1 = __shfl_xor(j1, xm), f2 = __shfl_xor(j2, xm);
  float a0 = d0, a1 = d1, a2 = d2;
  int   b0 = j0, b1 = j1, b2 = j2;
  float od0, od1, od2; int oj0, oj1, oj2;
  #pragma unroll
  for (int r = 0; r < 3; ++r) {
    bool ta = (a0 < e0) || (a0 == e0 && b0 < f0);
    float sd = ta ? a0 : e0; int sj = ta ? b0 : f0;
    a0 = ta ? a1 : a0;  b0 = ta ? b1 : b0;
    a1 = ta ? a2 : a1;  b1 = ta ? b2 : b1;
    a2 = ta ? FINF : a2;
    e0 = ta ? e0 : e1;  f0 = ta ? f0 : f1;
    e1 = ta ? e1 : e2;  f1 = ta ? f1 : f2;
    e2 = ta ? e2 : FINF;
    if (r == 0) { od0 = sd; oj0 = sj; }
    else if (r == 1) { od1 = sd; oj1 = sj; }
    else { od2 = sd; oj2 = sj; }
  }
  d0 = od0; j0 = oj0; d1 = od1; j1 = oj1; d2 = od2; j2 = oj2;
}

// ---------------- prep: xr[i] = (x, y, z, x^2+y^2+z^2) for all B*N points ----
extern "C" __global__ void __launch_bounds__(256)
prep_kernel(const float* __restrict__ x, float4* __restrict__ xr) {
  const int i = blockIdx.x * 256 + threadIdx.x;   // 0..131071
  const float rx = x[i*3+0], ry = x[i*3+1], rz = x[i*3+2];
  xr[i] = make_float4(rx, ry, rz, rx*rx + ry*ry + rz*rz);
}

// ---------------- kNN 1: block-per-query, 4 waves x 4096 refs, k=32, 3-D -----
extern "C" __global__ void __launch_bounds__(256)
knn1_kernel(const float4* __restrict__ xr, const int* __restrict__ sidx1,
            int* __restrict__ idx1) {
  __shared__ unsigned long long KS[128];
  const int w = threadIdx.x >> 6, lane = threadIdx.x & 63;
  const int gq = blockIdx.x;                  // 0..4095
  const int b = gq >> 9, q = gq & (NS1 - 1);
  const float4* xb = xr + (size_t)b * NPTS;
  const float4 Q = xb[sidx1[q]];
  const float qq = Q.w;
  const float4* xw = xb + w * 4096;
  unsigned long long lkey = ~0ull, tau = ~0ull;
  #pragma unroll 2
  for (int t = 0; t < 64; ++t) {
    const int jj = t*64 + lane;
    const float4 r = xw[jj];
    const float d = (qq - 2.0f*(Q.x*r.x + Q.y*r.y + Q.z*r.z)) + r.w;
    const unsigned long long key =
        ((unsigned long long)sortkey(d) << 32) | (unsigned)(w*4096 + jj);
    topk32_tile(key, lane, lkey, tau);
  }
  if (lane < 32) KS[w*32 + lane] = lkey;
  __syncthreads();
  if (w == 0) {
    lkey = ~0ull; tau = ~0ull;
    #pragma unroll
    for (int t = 0; t < 2; ++t) {
      const unsigned long long key = KS[t*64 + lane];
      topk32_tile(key, lane, lkey, tau);
    }
    if (lane < 32) idx1[gq*KNN + lane] = (int)(unsigned)lkey;
  }
}

// ---------------- MLP1 (3->64 relu ->64) + maxpool over 32 nbrs ---------------
extern "C" __global__ void __launch_bounds__(256)
mlp1_kernel(const float* __restrict__ x, const int* __restrict__ sidx1,
            const int* __restrict__ idx1,
            const float* __restrict__ W1, const float* __restrict__ b1,
            const float* __restrict__ W2, const float* __restrict__ b2,
            float* __restrict__ feat1, float* __restrict__ rr1,
            float* __restrict__ samp1) {
  __shared__ float P[32][3];
  __shared__ float H[32][64];
  __shared__ float PM[4][64];
  const int tid = threadIdx.x;
  const int gq = blockIdx.x;                  // 0..4095
  const int b = gq >> 9, q = gq & (NS1-1);
  const float* xb = x + (size_t)b * NPTS * 3;
  const int* nb = idx1 + gq * KNN;
  if (tid < 96) { int n = tid/3, d = tid - n*3; P[n][d] = xb[nb[n]*3 + d]; }
  __syncthreads();
  #pragma unroll
  for (int i = 0; i < 8; ++i) {
    int e = tid + 256*i, n = e >> 6, c = e & 63;
    float h = b1[c] + P[n][0]*W1[c] + P[n][1]*W1[64+c] + P[n][2]*W1[128+c];
    H[n][c] = fmaxf(h, 0.0f);
  }
  __syncthreads();
  const int g = tid >> 6, c = tid & 63;
  float acc[8];
  #pragma unroll
  for (int k = 0; k < 8; ++k) acc[k] = 0.0f;
  for (int j = 0; j < 64; j += 4) {
    float w0 = W2[j*64+c], w1 = W2[(j+1)*64+c], w2 = W2[(j+2)*64+c], w3 = W2[(j+3)*64+c];
    #pragma unroll
    for (int k = 0; k < 8; ++k) {
      float4 h4 = *(const float4*)&H[g*8+k][j];
      acc[k] = fmaf(h4.w, w3, fmaf(h4.z, w2, fmaf(h4.y, w1, fmaf(h4.x, w0, acc[k]))));
    }
  }
  float m = acc[0];
  #pragma unroll
  for (int k = 1; k < 8; ++k) m = fmaxf(m, acc[k]);
  PM[g][c] = m;
  __syncthreads();
  if (tid < 64) {
    float v = fmaxf(fmaxf(PM[0][tid], PM[1][tid]), fmaxf(PM[2][tid], PM[3][tid])) + b2[tid];
    feat1[(size_t)gq*64 + tid] = v;
    float s = v*v;
    #pragma unroll
    for (int off = 32; off; off >>= 1) s += __shfl_xor(s, off);
    if (tid == 0) rr1[gq] = s;
  } else if (tid < 67) {
    int d = tid - 64;
    samp1[(size_t)gq*3 + d] = xb[sidx1[q]*3 + d];
  }
}

// ---------------- kNN 2: queries feat1[sidx2] (128/b), refs feat1 (512/b), 64-D
extern "C" __global__ void __launch_bounds__(256)
knn2_kernel(const float* __restrict__ feat1, const float* __restrict__ rr1,
            const int* __restrict__ sidx2, int* __restrict__ idx2) {
  __shared__ float qrow[4][64];
  const int w = threadIdx.x >> 6, lane = threadIdx.x & 63;
  const int gq = blockIdx.x*4 + w;            // 0..1023
  const int b = gq >> 7, q = gq & (NS2-1);
  const int sq = sidx2[q];
  const float* f1b = feat1 + (size_t)b * NS1 * 64;
  const float* rrb = rr1 + b * NS1;
  qrow[w][lane] = f1b[sq*64 + lane];
  __syncthreads();
  const float qq = rrb[sq];
  unsigned long long lkey = ~0ull, tau = ~0ull;
  for (int t = 0; t < NS1/64; ++t) {
    const int j = t*64 + lane;
    const float* rrow = f1b + j*64;
    float dot = 0.0f;
    #pragma unroll
    for (int f = 0; f < 64; f += 4) {
      float4 r4 = *(const float4*)(rrow + f);
      dot = fmaf(qrow[w][f+3], r4.w, fmaf(qrow[w][f+2], r4.z,
            fmaf(qrow[w][f+1], r4.y, fmaf(qrow[w][f+0], r4.x, dot))));
    }
    const float d = (qq - 2.0f*dot) + rrb[j];
    const unsigned long long key =
        ((unsigned long long)sortkey(d) << 32) | (unsigned)j;
    topk32_round(key, lane, lkey, tau);
  }
  if (lane < 32) idx2[gq*KNN + lane] = (int)(unsigned)lkey;
}

// ---------------- MLP2 (64->128 relu ->128) + maxpool over 32 nbrs -----------
extern "C" __global__ void __launch_bounds__(256)
mlp2_kernel(const float* __restrict__ feat1, const int* __restrict__ idx2,
            const float* __restrict__ W1, const float* __restrict__ b1,
            const float* __restrict__ W2, const float* __restrict__ b2,
            float* __restrict__ feat2) {
  __shared__ float Gm[32][64];
  __shared__ float H[32][128];
  __shared__ float PM[2][128];
  const int tid = threadIdx.x;
  const int gq = blockIdx.x;                  // 0..1023
  const int b = gq >> 7;
  const float* f1b = feat1 + (size_t)b * NS1 * 64;
  const int* nb = idx2 + gq * KNN;
  #pragma unroll
  for (int i = 0; i < 8; ++i) {
    int e = tid + 256*i, n = e >> 6, f = e & 63;
    Gm[n][f] = f1b[nb[n]*64 + f];
  }
  __syncthreads();
  #pragma unroll
  for (int i = 0; i < 16; ++i) {
    int e = tid + 256*i, n = e >> 7, c = e & 127;
    float h = b1[c];
    for (int f = 0; f < 64; f += 4) {
      float4 g4 = *(const float4*)&Gm[n][f];
      h = fmaf(g4.x, W1[f*128+c], h);
      h = fmaf(g4.y, W1[(f+1)*128+c], h);
      h = fmaf(g4.z, W1[(f+2)*128+c], h);
      h = fmaf(g4.w, W1[(f+3)*128+c], h);
    }
    H[n][c] = fmaxf(h, 0.0f);
  }
  __syncthreads();
  const int g = tid >> 7, c = tid & 127;
  float acc[16];
  #pragma unroll
  for (int k = 0; k < 16; ++k) acc[k] = 0.0f;
  for (int j = 0; j < 128; j += 4) {
    float w0 = W2[j*128+c], w1 = W2[(j+1)*128+c], w2 = W2[(j+2)*128+c], w3 = W2[(j+3)*128+c];
    #pragma unroll
    for (int k = 0; k < 16; ++k) {
      float4 h4 = *(const float4*)&H[g*16+k][j];
      acc[k] = fmaf(h4.w, w3, fmaf(h4.z, w2, fmaf(h4.y, w1, fmaf(h4.x, w0, acc[k]))));
    }
  }
  float m = acc[0];
  #pragma unroll
  for (int k = 1; k < 16; ++k) m = fmaxf(m, acc[k]);
  PM[g][c] = m;
  __syncthreads();
  if (tid < 128) feat2[(size_t)gq*128 + tid] = fmaxf(PM[0][tid], PM[1][tid]) + b2[tid];
}

// ------- fp1: kNN(samp1 vs coords2, k=3) + mean(feat2) + MLP(192->64 relu ->64)
extern "C" __global__ void __launch_bounds__(256)
fp1_kernel(const float* __restrict__ samp1, const int* __restrict__ sidx2,
           const float* __restrict__ feat1, const float* __restrict__ feat2,
           const float* __restrict__ W1, const float* __restrict__ b1,
           const float* __restrict__ W2, const float* __restrict__ b2,
           float* __restrict__ h1) {
  __shared__ float interp[4][128];
  __shared__ float hbuf[4][64];
  const int w = threadIdx.x >> 6, lane = threadIdx.x & 63;
  const int gq = blockIdx.x*4 + w;            // 0..4095
  const int b = gq >> 9, q = gq & (NS1-1);
  const float* s1b = samp1 + (size_t)b * NS1 * 3;
  const float qx = s1b[q*3+0], qy = s1b[q*3+1], qz = s1b[q*3+2];
  const float qq = qx*qx + qy*qy + qz*qz;
  float d0, d1; int j0i, j1i;
  {
    const int rs = sidx2[lane];
    const float rx = s1b[rs*3+0], ry = s1b[rs*3+1], rz = s1b[rs*3+2];
    d0 = (qq - 2.0f*(qx*rx+qy*ry+qz*rz)) + (rx*rx+ry*ry+rz*rz);
    j0i = lane;
  }
  {
    const int j = lane + 64;
    const int rs = sidx2[j];
    const float rx = s1b[rs*3+0], ry = s1b[rs*3+1], rz = s1b[rs*3+2];
    d1 = (qq - 2.0f*(qx*rx+qy*ry+qz*rz)) + (rx*rx+ry*ry+rz*rz);
    j1i = j;
  }
  if (d1 < d0) { float td = d0; d0 = d1; d1 = td; int tj = j0i; j0i = j1i; j1i = tj; }
  float dA = d0, dB = d1, dC = FINF;
  int   jA = j0i, jB = j1i, jC = 0;
  merge3(dA, jA, dB, jB, dC, jC, 1);
  merge3(dA, jA, dB, jB, dC, jC, 2);
  merge3(dA, jA, dB, jB, dC, jC, 4);
  merge3(dA, jA, dB, jB, dC, jC, 8);
  merge3(dA, jA, dB, jB, dC, jC, 16);
  merge3(dA, jA, dB, jB, dC, jC, 32);
  const int r0 = jA, r1 = jB, r2 = jC;
  const float* f2b = feat2 + (size_t)b * NS2 * 128;
  interp[w][lane] =
      (f2b[r0*128+lane] + f2b[r1*128+lane] + f2b[r2*128+lane]) * (1.0f/3.0f);
  interp[w][lane+64] =
      (f2b[r0*128+64+lane] + f2b[r1*128+64+lane] + f2b[r2*128+64+lane]) * (1.0f/3.0f);
  __syncthreads();
  const float* f1row = feat1 + (size_t)gq * 64;
  float h = b1[lane];
  for (int f = 0; f < 64; ++f)  h = fmaf(f1row[f], W1[f*64+lane], h);
  for (int f = 0; f < 128; ++f) h = fmaf(interp[w][f], W1[(64+f)*64+lane], h);
  hbuf[w][lane] = fmaxf(h, 0.0f);
  __syncthreads();
  float o = b2[lane];
  for (int f = 0; f < 64; ++f) o = fmaf(hbuf[w][f], W2[f*64+lane], o);
  h1[(size_t)gq*64 + lane] = o;
}

// ------- fp2a: kNN(x vs samp1, k=3). 4 threads/point, 128 refs each, shfl merge.
extern "C" __global__ void __launch_bounds__(256, 4)
fp2a_kernel(const float* __restrict__ x, const float* __restrict__ samp1,
            ushort4* __restrict__ knn3) {
  __shared__ float4 RS[NS1];
  const int tid = threadIdx.x;
  const int b = blockIdx.x >> 8;              // 256 blocks per batch
  const int pbase = (blockIdx.x & 255) * 64;
  for (int e = tid; e < NS1; e += 256) {
    const float rx = samp1[((size_t)b*NS1 + e)*3 + 0];
    const float ry = samp1[((size_t)b*NS1 + e)*3 + 1];
    const float rz = samp1[((size_t)b*NS1 + e)*3 + 2];
    RS[e] = make_float4(rx, ry, rz, rx*rx + ry*ry + rz*rz);
  }
  __syncthreads();
  const int p = pbase + (tid >> 2);
  const int q4 = tid & 3;
  const float* xb = x + (size_t)b * NPTS * 3;
  const float qx = xb[p*3+0], qy = xb[p*3+1], qz = xb[p*3+2];
  const float qq = qx*qx + qy*qy + qz*qz;
  float d0 = FINF, d1 = FINF, d2 = FINF;
  int j0 = 0, j1 = 0, j2 = 0;
  const float4* RQ = RS + q4*128;
  #pragma unroll 4
  for (int i = 0; i < 128; ++i) {
    const float4 r = RQ[i];
    const float dot = qx*r.x + qy*r.y + qz*r.z;
    const float d = (qq - 2.0f*dot) + r.w;
    const int j = q4*128 + i;
    const bool c2 = d < d2, c1 = d < d1, c0 = d < d0;
    d2 = c1 ? d1 : (c2 ? d : d2);  j2 = c1 ? j1 : (c2 ? j : j2);
    d1 = c0 ? d0 : (c1 ? d : d1);  j1 = c0 ? j0 : (c1 ? j : j1);
    d0 = c0 ? d : d0;              j0 = c0 ? j : j0;
  }
  merge3(d0, j0, d1, j1, d2, j2, 1);
  merge3(d0, j0, d1, j1, d2, j2, 2);
  if (q4 == 0) {
    ushort4 o;
    o.x = (unsigned short)j0; o.y = (unsigned short)j1;
    o.z = (unsigned short)j2; o.w = 0;
    knn3[(size_t)b*NPTS + p] = o;
  }
}

// ------- fp2b: interp(h1, knn3) + MLP(67->32 relu) @ folded (W2@fc) + sigmoid
extern "C" __global__ void __launch_bounds__(256, 4)
fp2b_kernel(const float* __restrict__ x, const ushort4* __restrict__ knn3,
            const float* __restrict__ h1,
            const float* __restrict__ W1, const float* __restrict__ b1,
            const float* __restrict__ W2, const float* __restrict__ b2,
            const float* __restrict__ fcW, const float* __restrict__ fcb,
            float* __restrict__ out) {
  __shared__ float Xe[64][68];
  __shared__ float W1s[67*32];
  __shared__ float Hs[64][36];
  __shared__ ushort4 kid[64];
  __shared__ float WcS[64];
  __shared__ float bcS[2];
  const int tid = threadIdx.x;
  const int b = blockIdx.x >> 8;
  const int pbase = (blockIdx.x & 255) * 64;
  const float* xb = x + (size_t)b * NPTS * 3;
  const float* h1b = h1 + (size_t)b * NS1 * 64;
  if (tid < 64) {
    kid[tid] = knn3[(size_t)b*NPTS + pbase + tid];
    Xe[tid][0] = xb[(pbase+tid)*3+0];
    Xe[tid][1] = xb[(pbase+tid)*3+1];
    Xe[tid][2] = xb[(pbase+tid)*3+2];
  }
  for (int e = tid; e < 67*32; e += 256) W1s[e] = W1[e];
  __syncthreads();
  {
    const int sub = tid >> 6, f = tid & 63;
    #pragma unroll 4
    for (int i = 0; i < 16; ++i) {
      const int p = i*4 + sub;
      const ushort4 kk = kid[p];
      const float v = (h1b[(int)kk.x*64 + f] + h1b[(int)kk.y*64 + f] +
                       h1b[(int)kk.z*64 + f]) * (1.0f/3.0f);
      Xe[p][3+f] = v;
    }
  }
  __syncthreads();
  if (tid < 64) {
    const int k = tid >> 1, col = tid & 1;
    float s = 0.0f;
    for (int c = 0; c < 32; ++c) s = fmaf(W2[k*32+c], fcW[c*2+col], s);
    WcS[k*2+col] = s;
  } else if (tid < 66) {
    const int col = tid & 1;
    float s = fcb[col];
    for (int c = 0; c < 32; ++c) s = fmaf(b2[c], fcW[c*2+col], s);
    bcS[col] = s;
  }
  {
    const int p = tid >> 2, c0 = (tid & 3) * 8;
    float acc[8];
    const float4 bb0 = *(const float4*)(b1 + c0);
    const float4 bb1 = *(const float4*)(b1 + c0 + 4);
    acc[0]=bb0.x; acc[1]=bb0.y; acc[2]=bb0.z; acc[3]=bb0.w;
    acc[4]=bb1.x; acc[5]=bb1.y; acc[6]=bb1.z; acc[7]=bb1.w;
    for (int f = 0; f < 67; ++f) {
      const float xv = Xe[p][f];
      const float4 w0 = *(const float4*)&W1s[f*32 + c0];
      const float4 w1 = *(const float4*)&W1s[f*32 + c0 + 4];
      acc[0] = fmaf(xv, w0.x, acc[0]);
      acc[1] = fmaf(xv, w0.y, acc[1]);
      acc[2] = fmaf(xv, w0.z, acc[2]);
      acc[3] = fmaf(xv, w0.w, acc[3]);
      acc[4] = fmaf(xv, w1.x, acc[4]);
      acc[5] = fmaf(xv, w1.y, acc[5]);
      acc[6] = fmaf(xv, w1.z, acc[6]);
      acc[7] = fmaf(xv, w1.w, acc[7]);
    }
    *(float4*)&Hs[p][c0]   = make_float4(fmaxf(acc[0],0.f), fmaxf(acc[1],0.f),
                                         fmaxf(acc[2],0.f), fmaxf(acc[3],0.f));
    *(float4*)&Hs[p][c0+4] = make_float4(fmaxf(acc[4],0.f), fmaxf(acc[5],0.f),
                                         fmaxf(acc[6],0.f), fmaxf(acc[7],0.f));
  }
  __syncthreads();
  if (tid < 128) {
    const int p = tid >> 1, col = tid & 1;
    float s = bcS[col];
    for (int c = 0; c < 32; ++c) s = fmaf(Hs[p][c], WcS[c*2+col], s);
    out[((size_t)b*NPTS + pbase + p)*2 + col] = 1.0f / (1.0f + expf(-s));
  }
}

extern "C" void kernel_launch(void* const* d_in, const int* in_sizes, int n_in,
                              void* d_out, int out_size, void* d_ws, size_t ws_size,
                              hipStream_t stream) {
  const float* x     = (const float*)d_in[0];
  const int*   sidx1 = (const int*)d_in[1];
  const int*   sidx2 = (const int*)d_in[2];
  const float* sa1W1 = (const float*)d_in[3];
  const float* sa1b1 = (const float*)d_in[4];
  const float* sa1W2 = (const float*)d_in[5];
  const float* sa1b2 = (const float*)d_in[6];
  const float* sa2W1 = (const float*)d_in[7];
  const float* sa2b1 = (const float*)d_in[8];
  const float* sa2W2 = (const float*)d_in[9];
  const float* sa2b2 = (const float*)d_in[10];
  const float* fp1W1 = (const float*)d_in[11];
  const float* fp1b1 = (const float*)d_in[12];
  const float* fp1W2 = (const float*)d_in[13];
  const float* fp1b2 = (const float*)d_in[14];
  const float* fp2W1 = (const float*)d_in[15];
  const float* fp2b1 = (const float*)d_in[16];
  const float* fp2W2 = (const float*)d_in[17];
  const float* fp2b2 = (const float*)d_in[18];
  const float* fcW   = (const float*)d_in[19];
  const float* fcb   = (const float*)d_in[20];
  float* out = (float*)d_out;

  char* ws = (char*)d_ws;
  // xr (2 MB) lives at ws+0 and is ONLY read by knn1 (first compute kernel);
  // the regions it overlaps (feat1/rr1/samp1/feat2/h1-head) are written by
  // kernels that run strictly after knn1 on the same stream.
  float4* xr   = (float4*)(ws + 0);         // 8*16384*16 = 2,097,152 B
  float* feat1 = (float*)(ws + 0);          // 8*512*64  f32 = 1,048,576 B
  float* rr1   = (float*)(ws + 1048576);    // 8*512         =    16,384 B
  float* samp1 = (float*)(ws + 1064960);    // 8*512*3       =    49,152 B
  float* feat2 = (float*)(ws + 1114112);    // 8*128*128     =   524,288 B
  float* h1    = (float*)(ws + 1638400);    // 8*512*64      = 1,048,576 B
  int*   idx1  = (int*)  (ws + 2686976);    // 8*512*32      =   524,288 B
  int*   idx2  = (int*)  (ws + 3211264);    // 8*128*32      =   131,072 B
  // knn3 reuses feat1's 1MB (feat1 dead after fp1_kernel): 131072 * 8B
  ushort4* knn3 = (ushort4*)(ws + 0);

  hipLaunchKernelGGL(prep_kernel, dim3(512), dim3(256), 0, stream, x, xr);
  hipLaunchKernelGGL(knn1_kernel, dim3(4096), dim3(256), 0, stream,
                     xr, sidx1, idx1);
  hipLaunchKernelGGL(mlp1_kernel, dim3(4096), dim3(256), 0, stream,
                     x, sidx1, idx1, sa1W1, sa1b1, sa1W2, sa1b2,
                     feat1, rr1, samp1);
  hipLaunchKernelGGL(knn2_kernel, dim3(256), dim3(256), 0, stream,
                     feat1, rr1, sidx2, idx2);
  hipLaunchKernelGGL(mlp2_kernel, dim3(1024), dim3(256), 0, stream,
                     feat1, idx2, sa2W1, sa2b1, sa2W2, sa2b2, feat2);
  hipLaunchKernelGGL(fp1_kernel, dim3(1024), dim3(256), 0, stream,
                     samp1, sidx2, feat1, feat2, fp1W1, fp1b1, fp1W2, fp1b2, h1);
  hipLaunchKernelGGL(fp2a_kernel, dim3(2048), dim3(256), 0, stream,
                     x, samp1, knn3);
  hipLaunchKernelGGL(fp2b_kernel, dim3(2048), dim3(256), 0, stream,
                     x, knn3, h1, fp2W1, fp2b1, fp2W2, fp2b2, fcW, fcb, out);
}

// Round 4
// 282.176 us; speedup vs baseline: 1.3514x; 1.3514x over previous
//
#include <hip/hip_runtime.h>
#include <hip/hip_bf16.h>

#define NB   8
#define NPTS 16384
#define NS1  512
#define NS2  128
#define KNN  32
#define FINF 3.402823466e+38f

// float -> order-preserving unsigned (handles tiny negative d2 from cancellation)
__device__ __forceinline__ unsigned sortkey(float f) {
  unsigned u = __float_as_uint(f);
  unsigned m = (u & 0x80000000u) ? 0xFFFFFFFFu : 0x80000000u;
  return u ^ m;
}

// Distributed exact running top-32 (by u64 key) across lanes 0..31 of a wave.
// (per-insert tau update variant — used by knn2)
__device__ __forceinline__ void topk32_round(unsigned long long key, int lane,
                                             unsigned long long& lkey,
                                             unsigned long long& tau) {
  unsigned long long mask = __ballot(key < tau);
  while (mask) {
    int src = __ffsll(mask) - 1;
    mask &= mask - 1;
    unsigned long long cand = __shfl(key, src);
    if (cand < tau) {               // re-check: tau may have shrunk
      unsigned long long up = __shfl_up(lkey, 1);
      if (lane == 0) up = 0ull;
      unsigned long long nk = (lkey < cand) ? lkey : (up < cand ? cand : up);
      if (lane < 32) lkey = nk;
      tau = __shfl(lkey, 31);
    }
  }
}

// Merge this lane's sorted top-3 (d,j) with xor-partner's, lexicographic (d, j).
__device__ __forceinline__ void merge3(float& d0, int& j0, float& d1, int& j1,
                                       float& d2, int& j2, int xm) {
  float e0 = __shfl_xor(d0, xm), e1 = __shfl_xor(d1, xm), e2 = __shfl_xor(d2, xm);
  int   f0 = __shfl_xor(j0, xm), f1 = __shfl_xor(j1, xm), f2 = __shfl_xor(j2, xm);
  float a0 = d0, a1 = d1, a2 = d2;
  int   b0 = j0, b1 = j1, b2 = j2;
  float od0, od1, od2; int oj0, oj1, oj2;
  #pragma unroll
  for (int r = 0; r < 3; ++r) {
    bool ta = (a0 < e0) || (a0 == e0 && b0 < f0);
    float sd = ta ? a0 : e0; int sj = ta ? b0 : f0;
    a0 = ta ? a1 : a0;  b0 = ta ? b1 : b0;
    a1 = ta ? a2 : a1;  b1 = ta ? b2 : b1;
    a2 = ta ? FINF : a2;
    e0 = ta ? e0 : e1;  f0 = ta ? f0 : f1;
    e1 = ta ? e1 : e2;  f1 = ta ? f1 : f2;
    e2 = ta ? e2 : FINF;
    if (r == 0) { od0 = sd; oj0 = sj; }
    else if (r == 1) { od1 = sd; oj1 = sj; }
    else { od2 = sd; oj2 = sj; }
  }
  d0 = od0; j0 = oj0; d1 = od1; j1 = oj1; d2 = od2; j2 = oj2;
}

// ---------------- prep: xr[i] = (x, y, z, x^2+y^2+z^2) for all B*N points ----
extern "C" __global__ void __launch_bounds__(256)
prep_kernel(const float* __restrict__ x, float4* __restrict__ xr) {
  const int i = blockIdx.x * 256 + threadIdx.x;   // 0..131071
  const float rx = x[i*3+0], ry = x[i*3+1], rz = x[i*3+2];
  xr[i] = make_float4(rx, ry, rz, rx*rx + ry*ry + rz*rz);
}

// ---- kNN 1: wave-per-query, per-insert tau, readlane broadcasts, prefetch ----
extern "C" __global__ void __launch_bounds__(256)
knn1_kernel(const float4* __restrict__ xr, const int* __restrict__ sidx1,
            int* __restrict__ idx1) {
  const int w = threadIdx.x >> 6, lane = threadIdx.x & 63;
  const int gq = blockIdx.x * 4 + w;          // 0..4095
  const int b = gq >> 9, q = gq & (NS1 - 1);
  const float4* xb = xr + (size_t)b * NPTS;
  const float4 Q = xb[sidx1[q]];
  unsigned long long lkey = ~0ull, tau = ~0ull;
  float4 r = xb[lane];
  for (int t = 0; t < NPTS/64; ++t) {
    float4 rn = r;
    if (t < NPTS/64 - 1) rn = xb[(t+1)*64 + lane];   // prefetch next tile
    const float d = (Q.w - 2.0f*(Q.x*r.x + Q.y*r.y + Q.z*r.z)) + r.w;
    const unsigned long long key =
        ((unsigned long long)sortkey(d) << 32) | (unsigned)(t*64 + lane);
    unsigned long long mask = __ballot(key < tau);
    while (mask) {
      const int src = (int)(__ffsll((long long)mask) - 1);   // wave-uniform
      mask &= mask - 1;
      const unsigned clo = (unsigned)__builtin_amdgcn_readlane((int)(unsigned)key, src);
      const unsigned chi = (unsigned)__builtin_amdgcn_readlane((int)(unsigned)(key >> 32), src);
      const unsigned long long cand = ((unsigned long long)chi << 32) | clo;
      if (cand < tau) {             // scalar-scalar: tau may have shrunk
        unsigned long long up = __shfl_up(lkey, 1);
        if (lane == 0) up = 0ull;
        unsigned long long nk = (lkey < cand) ? lkey : (up < cand ? cand : up);
        if (lane < 32) lkey = nk;
        const unsigned tlo = (unsigned)__builtin_amdgcn_readlane((int)(unsigned)lkey, 31);
        const unsigned thi = (unsigned)__builtin_amdgcn_readlane((int)(unsigned)(lkey >> 32), 31);
        tau = ((unsigned long long)thi << 32) | tlo;
      }
    }
    r = rn;
  }
  if (lane < 32) idx1[gq*KNN + lane] = (int)(unsigned)lkey;
}

// ---------------- MLP1 (3->64 relu ->64) + maxpool over 32 nbrs ---------------
extern "C" __global__ void __launch_bounds__(256)
mlp1_kernel(const float* __restrict__ x, const int* __restrict__ sidx1,
            const int* __restrict__ idx1,
            const float* __restrict__ W1, const float* __restrict__ b1,
            const float* __restrict__ W2, const float* __restrict__ b2,
            float* __restrict__ feat1, float* __restrict__ rr1,
            float* __restrict__ samp1) {
  __shared__ float P[32][3];
  __shared__ float H[32][64];
  __shared__ float PM[4][64];
  const int tid = threadIdx.x;
  const int gq = blockIdx.x;                  // 0..4095
  const int b = gq >> 9, q = gq & (NS1-1);
  const float* xb = x + (size_t)b * NPTS * 3;
  const int* nb = idx1 + gq * KNN;
  if (tid < 96) { int n = tid/3, d = tid - n*3; P[n][d] = xb[nb[n]*3 + d]; }
  __syncthreads();
  #pragma unroll
  for (int i = 0; i < 8; ++i) {
    int e = tid + 256*i, n = e >> 6, c = e & 63;
    float h = b1[c] + P[n][0]*W1[c] + P[n][1]*W1[64+c] + P[n][2]*W1[128+c];
    H[n][c] = fmaxf(h, 0.0f);
  }
  __syncthreads();
  const int g = tid >> 6, c = tid & 63;
  float acc[8];
  #pragma unroll
  for (int k = 0; k < 8; ++k) acc[k] = 0.0f;
  for (int j = 0; j < 64; j += 4) {
    float w0 = W2[j*64+c], w1 = W2[(j+1)*64+c], w2 = W2[(j+2)*64+c], w3 = W2[(j+3)*64+c];
    #pragma unroll
    for (int k = 0; k < 8; ++k) {
      float4 h4 = *(const float4*)&H[g*8+k][j];
      acc[k] = fmaf(h4.w, w3, fmaf(h4.z, w2, fmaf(h4.y, w1, fmaf(h4.x, w0, acc[k]))));
    }
  }
  float m = acc[0];
  #pragma unroll
  for (int k = 1; k < 8; ++k) m = fmaxf(m, acc[k]);
  PM[g][c] = m;
  __syncthreads();
  if (tid < 64) {
    float v = fmaxf(fmaxf(PM[0][tid], PM[1][tid]), fmaxf(PM[2][tid], PM[3][tid])) + b2[tid];
    feat1[(size_t)gq*64 + tid] = v;
    float s = v*v;
    #pragma unroll
    for (int off = 32; off; off >>= 1) s += __shfl_xor(s, off);
    if (tid == 0) rr1[gq] = s;
  } else if (tid < 67) {
    int d = tid - 64;
    samp1[(size_t)gq*3 + d] = xb[sidx1[q]*3 + d];
  }
}

// ---------------- kNN 2: queries feat1[sidx2] (128/b), refs feat1 (512/b), 64-D
extern "C" __global__ void __launch_bounds__(256)
knn2_kernel(const float* __restrict__ feat1, const float* __restrict__ rr1,
            const int* __restrict__ sidx2, int* __restrict__ idx2) {
  __shared__ float qrow[4][64];
  const int w = threadIdx.x >> 6, lane = threadIdx.x & 63;
  const int gq = blockIdx.x*4 + w;            // 0..1023
  const int b = gq >> 7, q = gq & (NS2-1);
  const int sq = sidx2[q];
  const float* f1b = feat1 + (size_t)b * NS1 * 64;
  const float* rrb = rr1 + b * NS1;
  qrow[w][lane] = f1b[sq*64 + lane];
  __syncthreads();
  const float qq = rrb[sq];
  unsigned long long lkey = ~0ull, tau = ~0ull;
  for (int t = 0; t < NS1/64; ++t) {
    const int j = t*64 + lane;
    const float* rrow = f1b + j*64;
    float dot = 0.0f;
    #pragma unroll
    for (int f = 0; f < 64; f += 4) {
      float4 r4 = *(const float4*)(rrow + f);
      dot = fmaf(qrow[w][f+3], r4.w, fmaf(qrow[w][f+2], r4.z,
            fmaf(qrow[w][f+1], r4.y, fmaf(qrow[w][f+0], r4.x, dot))));
    }
    const float d = (qq - 2.0f*dot) + rrb[j];
    const unsigned long long key =
        ((unsigned long long)sortkey(d) << 32) | (unsigned)j;
    topk32_round(key, lane, lkey, tau);
  }
  if (lane < 32) idx2[gq*KNN + lane] = (int)(unsigned)lkey;
}

// ---------------- MLP2 (64->128 relu ->128) + maxpool over 32 nbrs -----------
extern "C" __global__ void __launch_bounds__(256)
mlp2_kernel(const float* __restrict__ feat1, const int* __restrict__ idx2,
            const float* __restrict__ W1, const float* __restrict__ b1,
            const float* __restrict__ W2, const float* __restrict__ b2,
            float* __restrict__ feat2) {
  __shared__ float Gm[32][64];
  __shared__ float H[32][128];
  __shared__ float PM[2][128];
  const int tid = threadIdx.x;
  const int gq = blockIdx.x;                  // 0..1023
  const int b = gq >> 7;
  const float* f1b = feat1 + (size_t)b * NS1 * 64;
  const int* nb = idx2 + gq * KNN;
  #pragma unroll
  for (int i = 0; i < 8; ++i) {
    int e = tid + 256*i, n = e >> 6, f = e & 63;
    Gm[n][f] = f1b[nb[n]*64 + f];
  }
  __syncthreads();
  #pragma unroll
  for (int i = 0; i < 16; ++i) {
    int e = tid + 256*i, n = e >> 7, c = e & 127;
    float h = b1[c];
    for (int f = 0; f < 64; f += 4) {
      float4 g4 = *(const float4*)&Gm[n][f];
      h = fmaf(g4.x, W1[f*128+c], h);
      h = fmaf(g4.y, W1[(f+1)*128+c], h);
      h = fmaf(g4.z, W1[(f+2)*128+c], h);
      h = fmaf(g4.w, W1[(f+3)*128+c], h);
    }
    H[n][c] = fmaxf(h, 0.0f);
  }
  __syncthreads();
  const int g = tid >> 7, c = tid & 127;
  float acc[16];
  #pragma unroll
  for (int k = 0; k < 16; ++k) acc[k] = 0.0f;
  for (int j = 0; j < 128; j += 4) {
    float w0 = W2[j*128+c], w1 = W2[(j+1)*128+c], w2 = W2[(j+2)*128+c], w3 = W2[(j+3)*128+c];
    #pragma unroll
    for (int k = 0; k < 16; ++k) {
      float4 h4 = *(const float4*)&H[g*16+k][j];
      acc[k] = fmaf(h4.w, w3, fmaf(h4.z, w2, fmaf(h4.y, w1, fmaf(h4.x, w0, acc[k]))));
    }
  }
  float m = acc[0];
  #pragma unroll
  for (int k = 1; k < 16; ++k) m = fmaxf(m, acc[k]);
  PM[g][c] = m;
  __syncthreads();
  if (tid < 128) feat2[(size_t)gq*128 + tid] = fmaxf(PM[0][tid], PM[1][tid]) + b2[tid];
}

// ------- fp1: kNN(samp1 vs coords2, k=3) + mean(feat2) + MLP(192->64 relu ->64)
extern "C" __global__ void __launch_bounds__(256)
fp1_kernel(const float* __restrict__ samp1, const int* __restrict__ sidx2,
           const float* __restrict__ feat1, const float* __restrict__ feat2,
           const float* __restrict__ W1, const float* __restrict__ b1,
           const float* __restrict__ W2, const float* __restrict__ b2,
           float* __restrict__ h1) {
  __shared__ float interp[4][128];
  __shared__ float hbuf[4][64];
  const int w = threadIdx.x >> 6, lane = threadIdx.x & 63;
  const int gq = blockIdx.x*4 + w;            // 0..4095
  const int b = gq >> 9, q = gq & (NS1-1);
  const float* s1b = samp1 + (size_t)b * NS1 * 3;
  const float qx = s1b[q*3+0], qy = s1b[q*3+1], qz = s1b[q*3+2];
  const float qq = qx*qx + qy*qy + qz*qz;
  float d0, d1; int j0i, j1i;
  {
    const int rs = sidx2[lane];
    const float rx = s1b[rs*3+0], ry = s1b[rs*3+1], rz = s1b[rs*3+2];
    d0 = (qq - 2.0f*(qx*rx+qy*ry+qz*rz)) + (rx*rx+ry*ry+rz*rz);
    j0i = lane;
  }
  {
    const int j = lane + 64;
    const int rs = sidx2[j];
    const float rx = s1b[rs*3+0], ry = s1b[rs*3+1], rz = s1b[rs*3+2];
    d1 = (qq - 2.0f*(qx*rx+qy*ry+qz*rz)) + (rx*rx+ry*ry+rz*rz);
    j1i = j;
  }
  if (d1 < d0) { float td = d0; d0 = d1; d1 = td; int tj = j0i; j0i = j1i; j1i = tj; }
  float dA = d0, dB = d1, dC = FINF;
  int   jA = j0i, jB = j1i, jC = 0;
  merge3(dA, jA, dB, jB, dC, jC, 1);
  merge3(dA, jA, dB, jB, dC, jC, 2);
  merge3(dA, jA, dB, jB, dC, jC, 4);
  merge3(dA, jA, dB, jB, dC, jC, 8);
  merge3(dA, jA, dB, jB, dC, jC, 16);
  merge3(dA, jA, dB, jB, dC, jC, 32);
  const int r0 = jA, r1 = jB, r2 = jC;
  const float* f2b = feat2 + (size_t)b * NS2 * 128;
  interp[w][lane] =
      (f2b[r0*128+lane] + f2b[r1*128+lane] + f2b[r2*128+lane]) * (1.0f/3.0f);
  interp[w][lane+64] =
      (f2b[r0*128+64+lane] + f2b[r1*128+64+lane] + f2b[r2*128+64+lane]) * (1.0f/3.0f);
  __syncthreads();
  const float* f1row = feat1 + (size_t)gq * 64;
  float h = b1[lane];
  for (int f = 0; f < 64; ++f)  h = fmaf(f1row[f], W1[f*64+lane], h);
  for (int f = 0; f < 128; ++f) h = fmaf(interp[w][f], W1[(64+f)*64+lane], h);
  hbuf[w][lane] = fmaxf(h, 0.0f);
  __syncthreads();
  float o = b2[lane];
  for (int f = 0; f < 64; ++f) o = fmaf(hbuf[w][f], W2[f*64+lane], o);
  h1[(size_t)gq*64 + lane] = o;
}

// ------- fp2a: kNN(x vs samp1, k=3). 4 threads/point, 128 refs each, shfl merge.
extern "C" __global__ void __launch_bounds__(256, 4)
fp2a_kernel(const float* __restrict__ x, const float* __restrict__ samp1,
            ushort4* __restrict__ knn3) {
  __shared__ float4 RS[NS1];
  const int tid = threadIdx.x;
  const int b = blockIdx.x >> 8;              // 256 blocks per batch
  const int pbase = (blockIdx.x & 255) * 64;
  for (int e = tid; e < NS1; e += 256) {
    const float rx = samp1[((size_t)b*NS1 + e)*3 + 0];
    const float ry = samp1[((size_t)b*NS1 + e)*3 + 1];
    const float rz = samp1[((size_t)b*NS1 + e)*3 + 2];
    RS[e] = make_float4(rx, ry, rz, rx*rx + ry*ry + rz*rz);
  }
  __syncthreads();
  const int p = pbase + (tid >> 2);
  const int q4 = tid & 3;
  const float* xb = x + (size_t)b * NPTS * 3;
  const float qx = xb[p*3+0], qy = xb[p*3+1], qz = xb[p*3+2];
  const float qq = qx*qx + qy*qy + qz*qz;
  float d0 = FINF, d1 = FINF, d2 = FINF;
  int j0 = 0, j1 = 0, j2 = 0;
  const float4* RQ = RS + q4*128;
  #pragma unroll 4
  for (int i = 0; i < 128; ++i) {
    const float4 r = RQ[i];
    const float dot = qx*r.x + qy*r.y + qz*r.z;
    const float d = (qq - 2.0f*dot) + r.w;
    const int j = q4*128 + i;
    const bool c2 = d < d2, c1 = d < d1, c0 = d < d0;
    d2 = c1 ? d1 : (c2 ? d : d2);  j2 = c1 ? j1 : (c2 ? j : j2);
    d1 = c0 ? d0 : (c1 ? d : d1);  j1 = c0 ? j0 : (c1 ? j : j1);
    d0 = c0 ? d : d0;              j0 = c0 ? j : j0;
  }
  merge3(d0, j0, d1, j1, d2, j2, 1);
  merge3(d0, j0, d1, j1, d2, j2, 2);
  if (q4 == 0) {
    ushort4 o;
    o.x = (unsigned short)j0; o.y = (unsigned short)j1;
    o.z = (unsigned short)j2; o.w = 0;
    knn3[(size_t)b*NPTS + p] = o;
  }
}

// ------- fp2b: interp(h1, knn3) + MLP(67->32 relu) @ folded (W2@fc) + sigmoid
extern "C" __global__ void __launch_bounds__(256, 4)
fp2b_kernel(const float* __restrict__ x, const ushort4* __restrict__ knn3,
            const float* __restrict__ h1,
            const float* __restrict__ W1, const float* __restrict__ b1,
            const float* __restrict__ W2, const float* __restrict__ b2,
            const float* __restrict__ fcW, const float* __restrict__ fcb,
            float* __restrict__ out) {
  __shared__ float Xe[64][68];
  __shared__ float W1s[67*32];
  __shared__ float Hs[64][36];
  __shared__ ushort4 kid[64];
  __shared__ float WcS[64];
  __shared__ float bcS[2];
  const int tid = threadIdx.x;
  const int b = blockIdx.x >> 8;
  const int pbase = (blockIdx.x & 255) * 64;
  const float* xb = x + (size_t)b * NPTS * 3;
  const float* h1b = h1 + (size_t)b * NS1 * 64;
  if (tid < 64) {
    kid[tid] = knn3[(size_t)b*NPTS + pbase + tid];
    Xe[tid][0] = xb[(pbase+tid)*3+0];
    Xe[tid][1] = xb[(pbase+tid)*3+1];
    Xe[tid][2] = xb[(pbase+tid)*3+2];
  }
  for (int e = tid; e < 67*32; e += 256) W1s[e] = W1[e];
  __syncthreads();
  {
    const int sub = tid >> 6, f = tid & 63;
    #pragma unroll 4
    for (int i = 0; i < 16; ++i) {
      const int p = i*4 + sub;
      const ushort4 kk = kid[p];
      const float v = (h1b[(int)kk.x*64 + f] + h1b[(int)kk.y*64 + f] +
                       h1b[(int)kk.z*64 + f]) * (1.0f/3.0f);
      Xe[p][3+f] = v;
    }
  }
  __syncthreads();
  if (tid < 64) {
    const int k = tid >> 1, col = tid & 1;
    float s = 0.0f;
    for (int c = 0; c < 32; ++c) s = fmaf(W2[k*32+c], fcW[c*2+col], s);
    WcS[k*2+col] = s;
  } else if (tid < 66) {
    const int col = tid & 1;
    float s = fcb[col];
    for (int c = 0; c < 32; ++c) s = fmaf(b2[c], fcW[c*2+col], s);
    bcS[col] = s;
  }
  {
    const int p = tid >> 2, c0 = (tid & 3) * 8;
    float acc[8];
    const float4 bb0 = *(const float4*)(b1 + c0);
    const float4 bb1 = *(const float4*)(b1 + c0 + 4);
    acc[0]=bb0.x; acc[1]=bb0.y; acc[2]=bb0.z; acc[3]=bb0.w;
    acc[4]=bb1.x; acc[5]=bb1.y; acc[6]=bb1.z; acc[7]=bb1.w;
    for (int f = 0; f < 67; ++f) {
      const float xv = Xe[p][f];
      const float4 w0 = *(const float4*)&W1s[f*32 + c0];
      const float4 w1 = *(const float4*)&W1s[f*32 + c0 + 4];
      acc[0] = fmaf(xv, w0.x, acc[0]);
      acc[1] = fmaf(xv, w0.y, acc[1]);
      acc[2] = fmaf(xv, w0.z, acc[2]);
      acc[3] = fmaf(xv, w0.w, acc[3]);
      acc[4] = fmaf(xv, w1.x, acc[4]);
      acc[5] = fmaf(xv, w1.y, acc[5]);
      acc[6] = fmaf(xv, w1.z, acc[6]);
      acc[7] = fmaf(xv, w1.w, acc[7]);
    }
    *(float4*)&Hs[p][c0]   = make_float4(fmaxf(acc[0],0.f), fmaxf(acc[1],0.f),
                                         fmaxf(acc[2],0.f), fmaxf(acc[3],0.f));
    *(float4*)&Hs[p][c0+4] = make_float4(fmaxf(acc[4],0.f), fmaxf(acc[5],0.f),
                                         fmaxf(acc[6],0.f), fmaxf(acc[7],0.f));
  }
  __syncthreads();
  if (tid < 128) {
    const int p = tid >> 1, col = tid & 1;
    float s = bcS[col];
    for (int c = 0; c < 32; ++c) s = fmaf(Hs[p][c], WcS[c*2+col], s);
    out[((size_t)b*NPTS + pbase + p)*2 + col] = 1.0f / (1.0f + expf(-s));
  }
}

extern "C" void kernel_launch(void* const* d_in, const int* in_sizes, int n_in,
                              void* d_out, int out_size, void* d_ws, size_t ws_size,
                              hipStream_t stream) {
  const float* x     = (const float*)d_in[0];
  const int*   sidx1 = (const int*)d_in[1];
  const int*   sidx2 = (const int*)d_in[2];
  const float* sa1W1 = (const float*)d_in[3];
  const float* sa1b1 = (const float*)d_in[4];
  const float* sa1W2 = (const float*)d_in[5];
  const float* sa1b2 = (const float*)d_in[6];
  const float* sa2W1 = (const float*)d_in[7];
  const float* sa2b1 = (const float*)d_in[8];
  const float* sa2W2 = (const float*)d_in[9];
  const float* sa2b2 = (const float*)d_in[10];
  const float* fp1W1 = (const float*)d_in[11];
  const float* fp1b1 = (const float*)d_in[12];
  const float* fp1W2 = (const float*)d_in[13];
  const float* fp1b2 = (const float*)d_in[14];
  const float* fp2W1 = (const float*)d_in[15];
  const float* fp2b1 = (const float*)d_in[16];
  const float* fp2W2 = (const float*)d_in[17];
  const float* fp2b2 = (const float*)d_in[18];
  const float* fcW   = (const float*)d_in[19];
  const float* fcb   = (const float*)d_in[20];
  float* out = (float*)d_out;

  char* ws = (char*)d_ws;
  // xr (2 MB) lives at ws+0 and is ONLY read by knn1 (first compute kernel);
  // the regions it overlaps (feat1/rr1/samp1/feat2/h1-head) are written by
  // kernels that run strictly after knn1 on the same stream.
  float4* xr   = (float4*)(ws + 0);         // 8*16384*16 = 2,097,152 B
  float* feat1 = (float*)(ws + 0);          // 8*512*64  f32 = 1,048,576 B
  float* rr1   = (float*)(ws + 1048576);    // 8*512         =    16,384 B
  float* samp1 = (float*)(ws + 1064960);    // 8*512*3       =    49,152 B
  float* feat2 = (float*)(ws + 1114112);    // 8*128*128     =   524,288 B
  float* h1    = (float*)(ws + 1638400);    // 8*512*64      = 1,048,576 B
  int*   idx1  = (int*)  (ws + 2686976);    // 8*512*32      =   524,288 B
  int*   idx2  = (int*)  (ws + 3211264);    // 8*128*32      =   131,072 B
  // knn3 reuses feat1's 1MB (feat1 dead after fp1_kernel): 131072 * 8B
  ushort4* knn3 = (ushort4*)(ws + 0);

  hipLaunchKernelGGL(prep_kernel, dim3(512), dim3(256), 0, stream, x, xr);
  hipLaunchKernelGGL(knn1_kernel, dim3(1024), dim3(256), 0, stream,
                     xr, sidx1, idx1);
  hipLaunchKernelGGL(mlp1_kernel, dim3(4096), dim3(256), 0, stream,
                     x, sidx1, idx1, sa1W1, sa1b1, sa1W2, sa1b2,
                     feat1, rr1, samp1);
  hipLaunchKernelGGL(knn2_kernel, dim3(256), dim3(256), 0, stream,
                     feat1, rr1, sidx2, idx2);
  hipLaunchKernelGGL(mlp2_kernel, dim3(1024), dim3(256), 0, stream,
                     feat1, idx2, sa2W1, sa2b1, sa2W2, sa2b2, feat2);
  hipLaunchKernelGGL(fp1_kernel, dim3(1024), dim3(256), 0, stream,
                     samp1, sidx2, feat1, feat2, fp1W1, fp1b1, fp1W2, fp1b2, h1);
  hipLaunchKernelGGL(fp2a_kernel, dim3(2048), dim3(256), 0, stream,
                     x, samp1, knn3);
  hipLaunchKernelGGL(fp2b_kernel, dim3(2048), dim3(256), 0, stream,
                     x, knn3, h1, fp2W1, fp2b1, fp2W2, fp2b2, fcW, fcb, out);
}

// Round 7
// 262.098 us; speedup vs baseline: 1.4549x; 1.0766x over previous
//
#include <hip/hip_runtime.h>
#include <hip/hip_bf16.h>

#define NB   8
#define NPTS 16384
#define NS1  512
#define NS2  128
#define KNN  32
#define FINF 3.402823466e+38f

// float -> order-preserving unsigned (handles tiny negative d2 from cancellation)
__device__ __forceinline__ unsigned sortkey(float f) {
  unsigned u = __float_as_uint(f);
  unsigned m = (u & 0x80000000u) ? 0xFFFFFFFFu : 0x80000000u;
  return u ^ m;
}

__device__ __forceinline__ unsigned long long rl64(unsigned long long v, int lane) {
  const unsigned lo = (unsigned)__builtin_amdgcn_readlane((int)(unsigned)v, lane);
  const unsigned hi = (unsigned)__builtin_amdgcn_readlane((int)(unsigned)(v >> 32), lane);
  return ((unsigned long long)hi << 32) | lo;
}

// shfl_up by 1 over lanes 0..31 via DPP row_shr:1 (no LDS). Row boundaries:
// lane0 -> 0 (bound_ctrl), lane16 patched with readlane(15) + select.
// Lanes >=32 produce garbage (unused by callers).
__device__ __forceinline__ unsigned long long shup1_dpp(unsigned long long v, bool is16) {
  const int lo = (int)(unsigned)v, hi = (int)(unsigned)(v >> 32);
  const int ulo = __builtin_amdgcn_update_dpp(0, lo, 0x111, 0xf, 0xf, true);
  const int uhi = __builtin_amdgcn_update_dpp(0, hi, 0x111, 0xf, 0xf, true);
  const int flo = __builtin_amdgcn_readlane(lo, 15);
  const int fhi = __builtin_amdgcn_readlane(hi, 15);
  const unsigned rlo = (unsigned)(is16 ? flo : ulo);
  const unsigned rhi = (unsigned)(is16 ? fhi : uhi);
  return ((unsigned long long)rhi << 32) | rlo;
}

// Distributed exact running top-32 (by u64 key) across lanes 0..31 of a wave.
// per-insert tau update; readlane broadcasts; DPP shift.
__device__ __forceinline__ void topk32_round(unsigned long long key, int lane,
                                             unsigned long long& lkey,
                                             unsigned long long& tau) {
  const bool is16 = (lane == 16);
  unsigned long long mask = __ballot(key < tau);
  while (mask) {
    const int src = (int)(__ffsll((long long)mask) - 1);   // wave-uniform
    mask &= mask - 1;
    const unsigned long long cand = rl64(key, src);
    if (cand < tau) {               // scalar compare: tau may have shrunk
      const unsigned long long up = shup1_dpp(lkey, is16);
      const unsigned long long nk = (lkey < cand) ? lkey : (up < cand ? cand : up);
      if (lane < 32) lkey = nk;
      tau = rl64(lkey, 31);
    }
  }
}

// Merge this lane's sorted top-3 (d,j) with xor-partner's, lexicographic (d, j).
__device__ __forceinline__ void merge3(float& d0, int& j0, float& d1, int& j1,
                                       float& d2, int& j2, int xm) {
  float e0 = __shfl_xor(d0, xm), e1 = __shfl_xor(d1, xm), e2 = __shfl_xor(d2, xm);
  int   f0 = __shfl_xor(j0, xm), f1 = __shfl_xor(j1, xm), f2 = __shfl_xor(j2, xm);
  float a0 = d0, a1 = d1, a2 = d2;
  int   b0 = j0, b1 = j1, b2 = j2;
  float od0, od1, od2; int oj0, oj1, oj2;
  #pragma unroll
  for (int r = 0; r < 3; ++r) {
    bool ta = (a0 < e0) || (a0 == e0 && b0 < f0);
    float sd = ta ? a0 : e0; int sj = ta ? b0 : f0;
    a0 = ta ? a1 : a0;  b0 = ta ? b1 : b0;
    a1 = ta ? a2 : a1;  b1 = ta ? b2 : b1;
    a2 = ta ? FINF : a2;
    e0 = ta ? e0 : e1;  f0 = ta ? f0 : f1;
    e1 = ta ? e1 : e2;  f1 = ta ? f1 : f2;
    e2 = ta ? e2 : FINF;
    if (r == 0) { od0 = sd; oj0 = sj; }
    else if (r == 1) { od1 = sd; oj1 = sj; }
    else { od2 = sd; oj2 = sj; }
  }
  d0 = od0; j0 = oj0; d1 = od1; j1 = oj1; d2 = od2; j2 = oj2;
}

// ---------------- prep: xr[i] = (x, y, z, x^2+y^2+z^2) for all B*N points ----
extern "C" __global__ void __launch_bounds__(256)
prep_kernel(const float* __restrict__ x, float4* __restrict__ xr) {
  const int i = blockIdx.x * 256 + threadIdx.x;   // 0..131071
  const float rx = x[i*3+0], ry = x[i*3+1], rz = x[i*3+2];
  xr[i] = make_float4(rx, ry, rz, rx*rx + ry*ry + rz*rz);
}

// per-tile distance + top-32 maintenance (insert path: readlane + DPP)
#define PROC(rr, jbase)                                                       \
  {                                                                           \
    const float d = (Q.w - 2.0f*(Q.x*rr.x + Q.y*rr.y + Q.z*rr.z)) + rr.w;     \
    const unsigned long long key =                                            \
        ((unsigned long long)sortkey(d) << 32) | (unsigned)((jbase) + lane);  \
    topk32_round(key, lane, lkey, tau);                                       \
  }

// ---- kNN 1: wave-per-query, 8-deep prefetch ring, per-insert tau, DPP insert
extern "C" __global__ void __launch_bounds__(256)
knn1_kernel(const float4* __restrict__ xr, const int* __restrict__ sidx1,
            int* __restrict__ idx1) {
  const int w = threadIdx.x >> 6, lane = threadIdx.x & 63;
  const int gq = blockIdx.x * 4 + w;          // 0..4095
  const int b = gq >> 9, q = gq & (NS1 - 1);
  const float4* xb = xr + (size_t)b * NPTS;
  const float4 Q = xb[sidx1[q]];
  unsigned long long lkey = ~0ull, tau = ~0ull;
  float4 r0 = xb[0*64+lane], r1 = xb[1*64+lane], r2 = xb[2*64+lane], r3 = xb[3*64+lane];
  float4 r4 = xb[4*64+lane], r5 = xb[5*64+lane], r6 = xb[6*64+lane], r7 = xb[7*64+lane];
  for (int t = 0; t < 256; t += 8) {
    PROC(r0, (t+0)*64);  r0 = xb[((t+ 8)&255)*64 + lane];
    PROC(r1, (t+1)*64);  r1 = xb[((t+ 9)&255)*64 + lane];
    PROC(r2, (t+2)*64);  r2 = xb[((t+10)&255)*64 + lane];
    PROC(r3, (t+3)*64);  r3 = xb[((t+11)&255)*64 + lane];
    PROC(r4, (t+4)*64);  r4 = xb[((t+12)&255)*64 + lane];
    PROC(r5, (t+5)*64);  r5 = xb[((t+13)&255)*64 + lane];
    PROC(r6, (t+6)*64);  r6 = xb[((t+14)&255)*64 + lane];
    PROC(r7, (t+7)*64);  r7 = xb[((t+15)&255)*64 + lane];
  }
  if (lane < 32) idx1[gq*KNN + lane] = (int)(unsigned)lkey;
}

// ---------------- MLP1 (3->64 relu ->64) + maxpool over 32 nbrs ---------------
extern "C" __global__ void __launch_bounds__(256)
mlp1_kernel(const float* __restrict__ x, const int* __restrict__ sidx1,
            const int* __restrict__ idx1,
            const float* __restrict__ W1, const float* __restrict__ b1,
            const float* __restrict__ W2, const float* __restrict__ b2,
            float* __restrict__ feat1, float* __restrict__ rr1,
            float* __restrict__ samp1) {
  __shared__ float P[32][3];
  __shared__ float H[32][64];
  __shared__ float PM[4][64];
  const int tid = threadIdx.x;
  const int gq = blockIdx.x;                  // 0..4095
  const int b = gq >> 9, q = gq & (NS1-1);
  const float* xb = x + (size_t)b * NPTS * 3;
  const int* nb = idx1 + gq * KNN;
  if (tid < 96) { int n = tid/3, d = tid - n*3; P[n][d] = xb[nb[n]*3 + d]; }
  __syncthreads();
  #pragma unroll
  for (int i = 0; i < 8; ++i) {
    int e = tid + 256*i, n = e >> 6, c = e & 63;
    float h = b1[c] + P[n][0]*W1[c] + P[n][1]*W1[64+c] + P[n][2]*W1[128+c];
    H[n][c] = fmaxf(h, 0.0f);
  }
  __syncthreads();
  const int g = tid >> 6, c = tid & 63;
  float acc[8];
  #pragma unroll
  for (int k = 0; k < 8; ++k) acc[k] = 0.0f;
  for (int j = 0; j < 64; j += 4) {
    float w0 = W2[j*64+c], w1 = W2[(j+1)*64+c], w2 = W2[(j+2)*64+c], w3 = W2[(j+3)*64+c];
    #pragma unroll
    for (int k = 0; k < 8; ++k) {
      float4 h4 = *(const float4*)&H[g*8+k][j];
      acc[k] = fmaf(h4.w, w3, fmaf(h4.z, w2, fmaf(h4.y, w1, fmaf(h4.x, w0, acc[k]))));
    }
  }
  float m = acc[0];
  #pragma unroll
  for (int k = 1; k < 8; ++k) m = fmaxf(m, acc[k]);
  PM[g][c] = m;
  __syncthreads();
  if (tid < 64) {
    float v = fmaxf(fmaxf(PM[0][tid], PM[1][tid]), fmaxf(PM[2][tid], PM[3][tid])) + b2[tid];
    feat1[(size_t)gq*64 + tid] = v;
    float s = v*v;
    #pragma unroll
    for (int off = 32; off; off >>= 1) s += __shfl_xor(s, off);
    if (tid == 0) rr1[gq] = s;
  } else if (tid < 67) {
    int d = tid - 64;
    samp1[(size_t)gq*3 + d] = xb[sidx1[q]*3 + d];
  }
}

// ---------------- kNN 2: queries feat1[sidx2] (128/b), refs feat1 (512/b), 64-D
extern "C" __global__ void __launch_bounds__(256)
knn2_kernel(const float* __restrict__ feat1, const float* __restrict__ rr1,
            const int* __restrict__ sidx2, int* __restrict__ idx2) {
  __shared__ float qrow[4][64];
  const int w = threadIdx.x >> 6, lane = threadIdx.x & 63;
  const int gq = blockIdx.x*4 + w;            // 0..1023
  const int b = gq >> 7, q = gq & (NS2-1);
  const int sq = sidx2[q];
  const float* f1b = feat1 + (size_t)b * NS1 * 64;
  const float* rrb = rr1 + b * NS1;
  qrow[w][lane] = f1b[sq*64 + lane];
  __syncthreads();
  const float qq = rrb[sq];
  unsigned long long lkey = ~0ull, tau = ~0ull;
  for (int t = 0; t < NS1/64; ++t) {
    const int j = t*64 + lane;
    const float* rrow = f1b + j*64;
    float dot = 0.0f;
    #pragma unroll
    for (int f = 0; f < 64; f += 4) {
      float4 r4 = *(const float4*)(rrow + f);
      dot = fmaf(qrow[w][f+3], r4.w, fmaf(qrow[w][f+2], r4.z,
            fmaf(qrow[w][f+1], r4.y, fmaf(qrow[w][f+0], r4.x, dot))));
    }
    const float d = (qq - 2.0f*dot) + rrb[j];
    const unsigned long long key =
        ((unsigned long long)sortkey(d) << 32) | (unsigned)j;
    topk32_round(key, lane, lkey, tau);
  }
  if (lane < 32) idx2[gq*KNN + lane] = (int)(unsigned)lkey;
}

// ---------------- MLP2 (64->128 relu ->128) + maxpool over 32 nbrs -----------
extern "C" __global__ void __launch_bounds__(256)
mlp2_kernel(const float* __restrict__ feat1, const int* __restrict__ idx2,
            const float* __restrict__ W1, const float* __restrict__ b1,
            const float* __restrict__ W2, const float* __restrict__ b2,
            float* __restrict__ feat2) {
  __shared__ float Gm[32][64];
  __shared__ float H[32][128];
  __shared__ float PM[2][128];
  const int tid = threadIdx.x;
  const int gq = blockIdx.x;                  // 0..1023
  const int b = gq >> 7;
  const float* f1b = feat1 + (size_t)b * NS1 * 64;
  const int* nb = idx2 + gq * KNN;
  #pragma unroll
  for (int i = 0; i < 8; ++i) {
    int e = tid + 256*i, n = e >> 6, f = e & 63;
    Gm[n][f] = f1b[nb[n]*64 + f];
  }
  __syncthreads();
  #pragma unroll
  for (int i = 0; i < 16; ++i) {
    int e = tid + 256*i, n = e >> 7, c = e & 127;
    float h = b1[c];
    for (int f = 0; f < 64; f += 4) {
      float4 g4 = *(const float4*)&Gm[n][f];
      h = fmaf(g4.x, W1[f*128+c], h);
      h = fmaf(g4.y, W1[(f+1)*128+c], h);
      h = fmaf(g4.z, W1[(f+2)*128+c], h);
      h = fmaf(g4.w, W1[(f+3)*128+c], h);
    }
    H[n][c] = fmaxf(h, 0.0f);
  }
  __syncthreads();
  const int g = tid >> 7, c = tid & 127;
  float acc[16];
  #pragma unroll
  for (int k = 0; k < 16; ++k) acc[k] = 0.0f;
  for (int j = 0; j < 128; j += 4) {
    float w0 = W2[j*128+c], w1 = W2[(j+1)*128+c], w2 = W2[(j+2)*128+c], w3 = W2[(j+3)*128+c];
    #pragma unroll
    for (int k = 0; k < 16; ++k) {
      float4 h4 = *(const float4*)&H[g*16+k][j];
      acc[k] = fmaf(h4.w, w3, fmaf(h4.z, w2, fmaf(h4.y, w1, fmaf(h4.x, w0, acc[k]))));
    }
  }
  float m = acc[0];
  #pragma unroll
  for (int k = 1; k < 16; ++k) m = fmaxf(m, acc[k]);
  PM[g][c] = m;
  __syncthreads();
  if (tid < 128) feat2[(size_t)gq*128 + tid] = fmaxf(PM[0][tid], PM[1][tid]) + b2[tid];
}

// ------- fp1: kNN(samp1 vs coords2, k=3) + mean(feat2) + MLP(192->64 relu ->64)
extern "C" __global__ void __launch_bounds__(256)
fp1_kernel(const float* __restrict__ samp1, const int* __restrict__ sidx2,
           const float* __restrict__ feat1, const float* __restrict__ feat2,
           const float* __restrict__ W1, const float* __restrict__ b1,
           const float* __restrict__ W2, const float* __restrict__ b2,
           float* __restrict__ h1) {
  __shared__ float interp[4][128];
  __shared__ float hbuf[4][64];
  const int w = threadIdx.x >> 6, lane = threadIdx.x & 63;
  const int gq = blockIdx.x*4 + w;            // 0..4095
  const int b = gq >> 9, q = gq & (NS1-1);
  const float* s1b = samp1 + (size_t)b * NS1 * 3;
  const float qx = s1b[q*3+0], qy = s1b[q*3+1], qz = s1b[q*3+2];
  const float qq = qx*qx + qy*qy + qz*qz;
  float d0, d1; int j0i, j1i;
  {
    const int rs = sidx2[lane];
    const float rx = s1b[rs*3+0], ry = s1b[rs*3+1], rz = s1b[rs*3+2];
    d0 = (qq - 2.0f*(qx*rx+qy*ry+qz*rz)) + (rx*rx+ry*ry+rz*rz);
    j0i = lane;
  }
  {
    const int j = lane + 64;
    const int rs = sidx2[j];
    const float rx = s1b[rs*3+0], ry = s1b[rs*3+1], rz = s1b[rs*3+2];
    d1 = (qq - 2.0f*(qx*rx+qy*ry+qz*rz)) + (rx*rx+ry*ry+rz*rz);
    j1i = j;
  }
  if (d1 < d0) { float td = d0; d0 = d1; d1 = td; int tj = j0i; j0i = j1i; j1i = tj; }
  float dA = d0, dB = d1, dC = FINF;
  int   jA = j0i, jB = j1i, jC = 0;
  merge3(dA, jA, dB, jB, dC, jC, 1);
  merge3(dA, jA, dB, jB, dC, jC, 2);
  merge3(dA, jA, dB, jB, dC, jC, 4);
  merge3(dA, jA, dB, jB, dC, jC, 8);
  merge3(dA, jA, dB, jB, dC, jC, 16);
  merge3(dA, jA, dB, jB, dC, jC, 32);
  const int r0 = jA, r1 = jB, r2 = jC;
  const float* f2b = feat2 + (size_t)b * NS2 * 128;
  interp[w][lane] =
      (f2b[r0*128+lane] + f2b[r1*128+lane] + f2b[r2*128+lane]) * (1.0f/3.0f);
  interp[w][lane+64] =
      (f2b[r0*128+64+lane] + f2b[r1*128+64+lane] + f2b[r2*128+64+lane]) * (1.0f/3.0f);
  __syncthreads();
  const float* f1row = feat1 + (size_t)gq * 64;
  float h = b1[lane];
  for (int f = 0; f < 64; ++f)  h = fmaf(f1row[f], W1[f*64+lane], h);
  for (int f = 0; f < 128; ++f) h = fmaf(interp[w][f], W1[(64+f)*64+lane], h);
  hbuf[w][lane] = fmaxf(h, 0.0f);
  __syncthreads();
  float o = b2[lane];
  for (int f = 0; f < 64; ++f) o = fmaf(hbuf[w][f], W2[f*64+lane], o);
  h1[(size_t)gq*64 + lane] = o;
}

// ------- fp2a: kNN(x vs samp1, k=3). 4 threads/point, 128 refs each, shfl merge.
extern "C" __global__ void __launch_bounds__(256, 4)
fp2a_kernel(const float* __restrict__ x, const float* __restrict__ samp1,
            ushort4* __restrict__ knn3) {
  __shared__ float4 RS[NS1];
  const int tid = threadIdx.x;
  const int b = blockIdx.x >> 8;              // 256 blocks per batch
  const int pbase = (blockIdx.x & 255) * 64;
  for (int e = tid; e < NS1; e += 256) {
    const float rx = samp1[((size_t)b*NS1 + e)*3 + 0];
    const float ry = samp1[((size_t)b*NS1 + e)*3 + 1];
    const float rz = samp1[((size_t)b*NS1 + e)*3 + 2];
    RS[e] = make_float4(rx, ry, rz, rx*rx + ry*ry + rz*rz);
  }
  __syncthreads();
  const int p = pbase + (tid >> 2);
  const int q4 = tid & 3;
  const float* xb = x + (size_t)b * NPTS * 3;
  const float qx = xb[p*3+0], qy = xb[p*3+1], qz = xb[p*3+2];
  const float qq = qx*qx + qy*qy + qz*qz;
  float d0 = FINF, d1 = FINF, d2 = FINF;
  int j0 = 0, j1 = 0, j2 = 0;
  const float4* RQ = RS + q4*128;
  #pragma unroll 4
  for (int i = 0; i < 128; ++i) {
    const float4 r = RQ[i];
    const float dot = qx*r.x + qy*r.y + qz*r.z;
    const float d = (qq - 2.0f*dot) + r.w;
    const int j = q4*128 + i;
    const bool c2 = d < d2, c1 = d < d1, c0 = d < d0;
    d2 = c1 ? d1 : (c2 ? d : d2);  j2 = c1 ? j1 : (c2 ? j : j2);
    d1 = c0 ? d0 : (c1 ? d : d1);  j1 = c0 ? j0 : (c1 ? j : j1);
    d0 = c0 ? d : d0;              j0 = c0 ? j : j0;
  }
  merge3(d0, j0, d1, j1, d2, j2, 1);
  merge3(d0, j0, d1, j1, d2, j2, 2);
  if (q4 == 0) {
    ushort4 o;
    o.x = (unsigned short)j0; o.y = (unsigned short)j1;
    o.z = (unsigned short)j2; o.w = 0;
    knn3[(size_t)b*NPTS + p] = o;
  }
}

// ------- fp2b: interp(h1, knn3) + MLP(67->32 relu) @ folded (W2@fc) + sigmoid
extern "C" __global__ void __launch_bounds__(256, 4)
fp2b_kernel(const float* __restrict__ x, const ushort4* __restrict__ knn3,
            const float* __restrict__ h1,
            const float* __restrict__ W1, const float* __restrict__ b1,
            const float* __restrict__ W2, const float* __restrict__ b2,
            const float* __restrict__ fcW, const float* __restrict__ fcb,
            float* __restrict__ out) {
  __shared__ float Xe[64][68];
  __shared__ float W1s[67*32];
  __shared__ float Hs[64][36];
  __shared__ ushort4 kid[64];
  __shared__ float WcS[64];
  __shared__ float bcS[2];
  const int tid = threadIdx.x;
  const int b = blockIdx.x >> 8;
  const int pbase = (blockIdx.x & 255) * 64;
  const float* xb = x + (size_t)b * NPTS * 3;
  const float* h1b = h1 + (size_t)b * NS1 * 64;
  if (tid < 64) {
    kid[tid] = knn3[(size_t)b*NPTS + pbase + tid];
    Xe[tid][0] = xb[(pbase+tid)*3+0];
    Xe[tid][1] = xb[(pbase+tid)*3+1];
    Xe[tid][2] = xb[(pbase+tid)*3+2];
  }
  for (int e = tid; e < 67*32; e += 256) W1s[e] = W1[e];
  __syncthreads();
  {
    const int sub = tid >> 6, f = tid & 63;
    #pragma unroll 4
    for (int i = 0; i < 16; ++i) {
      const int p = i*4 + sub;
      const ushort4 kk = kid[p];
      const float v = (h1b[(int)kk.x*64 + f] + h1b[(int)kk.y*64 + f] +
                       h1b[(int)kk.z*64 + f]) * (1.0f/3.0f);
      Xe[p][3+f] = v;
    }
  }
  __syncthreads();
  if (tid < 64) {
    const int k = tid >> 1, col = tid & 1;
    float s = 0.0f;
    for (int c = 0; c < 32; ++c) s = fmaf(W2[k*32+c], fcW[c*2+col], s);
    WcS[k*2+col] = s;
  } else if (tid < 66) {
    const int col = tid & 1;
    float s = fcb[col];
    for (int c = 0; c < 32; ++c) s = fmaf(b2[c], fcW[c*2+col], s);
    bcS[col] = s;
  }
  {
    const int p = tid >> 2, c0 = (tid & 3) * 8;
    float acc[8];
    const float4 bb0 = *(const float4*)(b1 + c0);
    const float4 bb1 = *(const float4*)(b1 + c0 + 4);
    acc[0]=bb0.x; acc[1]=bb0.y; acc[2]=bb0.z; acc[3]=bb0.w;
    acc[4]=bb1.x; acc[5]=bb1.y; acc[6]=bb1.z; acc[7]=bb1.w;
    for (int f = 0; f < 67; ++f) {
      const float xv = Xe[p][f];
      const float4 w0 = *(const float4*)&W1s[f*32 + c0];
      const float4 w1 = *(const float4*)&W1s[f*32 + c0 + 4];
      acc[0] = fmaf(xv, w0.x, acc[0]);
      acc[1] = fmaf(xv, w0.y, acc[1]);
      acc[2] = fmaf(xv, w0.z, acc[2]);
      acc[3] = fmaf(xv, w0.w, acc[3]);
      acc[4] = fmaf(xv, w1.x, acc[4]);
      acc[5] = fmaf(xv, w1.y, acc[5]);
      acc[6] = fmaf(xv, w1.z, acc[6]);
      acc[7] = fmaf(xv, w1.w, acc[7]);
    }
    *(float4*)&Hs[p][c0]   = make_float4(fmaxf(acc[0],0.f), fmaxf(acc[1],0.f),
                                         fmaxf(acc[2],0.f), fmaxf(acc[3],0.f));
    *(float4*)&Hs[p][c0+4] = make_float4(fmaxf(acc[4],0.f), fmaxf(acc[5],0.f),
                                         fmaxf(acc[6],0.f), fmaxf(acc[7],0.f));
  }
  __syncthreads();
  if (tid < 128) {
    const int p = tid >> 1, col = tid & 1;
    float s = bcS[col];
    for (int c = 0; c < 32; ++c) s = fmaf(Hs[p][c], WcS[c*2+col], s);
    out[((size_t)b*NPTS + pbase + p)*2 + col] = 1.0f / (1.0f + expf(-s));
  }
}

extern "C" void kernel_launch(void* const* d_in, const int* in_sizes, int n_in,
                              void* d_out, int out_size, void* d_ws, size_t ws_size,
                              hipStream_t stream) {
  const float* x     = (const float*)d_in[0];
  const int*   sidx1 = (const int*)d_in[1];
  const int*   sidx2 = (const int*)d_in[2];
  const float* sa1W1 = (const float*)d_in[3];
  const float* sa1b1 = (const float*)d_in[4];
  const float* sa1W2 = (const float*)d_in[5];
  const float* sa1b2 = (const float*)d_in[6];
  const float* sa2W1 = (const float*)d_in[7];
  const float* sa2b1 = (const float*)d_in[8];
  const float* sa2W2 = (const float*)d_in[9];
  const float* sa2b2 = (const float*)d_in[10];
  const float* fp1W1 = (const float*)d_in[11];
  const float* fp1b1 = (const float*)d_in[12];
  const float* fp1W2 = (const float*)d_in[13];
  const float* fp1b2 = (const float*)d_in[14];
  const float* fp2W1 = (const float*)d_in[15];
  const float* fp2b1 = (const float*)d_in[16];
  const float* fp2W2 = (const float*)d_in[17];
  const float* fp2b2 = (const float*)d_in[18];
  const float* fcW   = (const float*)d_in[19];
  const float* fcb   = (const float*)d_in[20];
  float* out = (float*)d_out;

  char* ws = (char*)d_ws;
  // xr (2 MB) lives at ws+0 and is ONLY read by knn1 (first compute kernel);
  // the regions it overlaps (feat1/rr1/samp1/feat2/h1-head) are written by
  // kernels that run strictly after knn1 on the same stream.
  float4* xr   = (float4*)(ws + 0);         // 8*16384*16 = 2,097,152 B
  float* feat1 = (float*)(ws + 0);          // 8*512*64  f32 = 1,048,576 B
  float* rr1   = (float*)(ws + 1048576);    // 8*512         =    16,384 B
  float* samp1 = (float*)(ws + 1064960);    // 8*512*3       =    49,152 B
  float* feat2 = (float*)(ws + 1114112);    // 8*128*128     =   524,288 B
  float* h1    = (float*)(ws + 1638400);    // 8*512*64      = 1,048,576 B
  int*   idx1  = (int*)  (ws + 2686976);    // 8*512*32      =   524,288 B
  int*   idx2  = (int*)  (ws + 3211264);    // 8*128*32      =   131,072 B
  // knn3 reuses feat1's 1MB (feat1 dead after fp1_kernel): 131072 * 8B
  ushort4* knn3 = (ushort4*)(ws + 0);

  hipLaunchKernelGGL(prep_kernel, dim3(512), dim3(256), 0, stream, x, xr);
  hipLaunchKernelGGL(knn1_kernel, dim3(1024), dim3(256), 0, stream,
                     xr, sidx1, idx1);
  hipLaunchKernelGGL(mlp1_kernel, dim3(4096), dim3(256), 0, stream,
                     x, sidx1, idx1, sa1W1, sa1b1, sa1W2, sa1b2,
                     feat1, rr1, samp1);
  hipLaunchKernelGGL(knn2_kernel, dim3(256), dim3(256), 0, stream,
                     feat1, rr1, sidx2, idx2);
  hipLaunchKernelGGL(mlp2_kernel, dim3(1024), dim3(256), 0, stream,
                     feat1, idx2, sa2W1, sa2b1, sa2W2, sa2b2, feat2);
  hipLaunchKernelGGL(fp1_kernel, dim3(1024), dim3(256), 0, stream,
                     samp1, sidx2, feat1, feat2, fp1W1, fp1b1, fp1W2, fp1b2, h1);
  hipLaunchKernelGGL(fp2a_kernel, dim3(2048), dim3(256), 0, stream,
                     x, samp1, knn3);
  hipLaunchKernelGGL(fp2b_kernel, dim3(2048), dim3(256), 0, stream,
                     x, knn3, h1, fp2W1, fp2b1, fp2W2, fp2b2, fcW, fcb, out);
}